// Round 7
// baseline (274.376 us; speedup 1.0000x reference)
//
#include <hip/hip_runtime.h>
#include <math.h>

#define D_DIM 512

typedef short short8v __attribute__((ext_vector_type(8)));
typedef unsigned short ushort8v __attribute__((ext_vector_type(8)));
typedef float f32x16 __attribute__((ext_vector_type(16)));

__device__ inline unsigned short f2bf(float f) {
    union { float f; unsigned int u; } a; a.f = f;
    unsigned int u = a.u;
    unsigned int r = (u + 0x7fffu + ((u >> 16) & 1u)) >> 16;  // RNE
    return (unsigned short)r;
}

// fast tanh: 1 - 2/(e^{2y}+1); saturates correctly at +-1
__device__ inline float fast_tanh(float y) {
    float e2 = __expf(2.f * y);
    return 1.f - __fdividef(2.f, e2 + 1.f);
}

// async 16B global -> LDS copy (per-lane 16B, wave-uniform LDS base + lane*16)
#define ASYNC_CP16(gp, lp) \
    __builtin_amdgcn_global_load_lds( \
        (const __attribute__((address_space(1))) void*)(gp), \
        (__attribute__((address_space(3))) void*)(lp), 16, 0, 0)

// ---------------------------------------------------------------------------
// wt: W[k][e] fp32 -> Wb2 stage-tiled bf16.
// Wb2 layout (ushort idx): stage s (32 k), then chunk = ((nt*2+ks)*2+half)*32+nl
// of 8 ushorts holding W[k=32s+16ks+8half+j][e=32nt+nl], j=0..7.
// Each 32KB stage slice is contiguous -> global_load_lds-friendly; each wave's
// fragment read is a contiguous 1KB -> LDS-conflict-free.
// ---------------------------------------------------------------------------
__global__ __launch_bounds__(256) void wt_kernel(const float* __restrict__ W,
                                                 unsigned short* __restrict__ Wb2) {
    __shared__ __align__(16) unsigned short lbuf[16384];   // 32 KiB
    const int s = blockIdx.x;          // 0..15
    const int tid = threadIdx.x;
    #pragma unroll
    for (int i = 0; i < 16; ++i) {
        int flat = tid + i * 256;      // 0..4095 float4-chunks of this stage
        int kr = flat >> 7;            // 0..31 (k within stage)
        int e4 = (flat & 127) * 4;
        float4 v = *(const float4*)(W + (size_t)(s * 32 + kr) * D_DIM + e4);
        int ks = kr >> 4, half = (kr >> 3) & 1, j = kr & 7;
        float vv[4] = {v.x, v.y, v.z, v.w};
        #pragma unroll
        for (int q = 0; q < 4; ++q) {
            int e = e4 + q, nt = e >> 5, nl = e & 31;
            lbuf[(((nt * 2 + ks) * 2 + half) * 32 + nl) * 8 + j] = f2bf(vv[q]);
        }
    }
    __syncthreads();
    #pragma unroll
    for (int i = 0; i < 8; ++i) {
        int c = tid + i * 256;         // 0..2047 8-ushort chunks
        *(ushort8v*)(Wb2 + (size_t)s * 16384 + c * 8) = *(const ushort8v*)&lbuf[c * 8];
    }
}

// ---------------------------------------------------------------------------
// MFMA GEMM + fused tanh/dot-u epilogue.
// 256 thr = 4 waves; tile 64 rows x 512 cols; K in 16 stages of 32.
// W staged via async global_load_lds into double-buffered LDS (conflict-free
// fragment reads); x converted fp32->bf16 in-register, double-buffered LDS.
// Single barrier per stage: next stage's DMA+loads fly under current MFMAs.
// ---------------------------------------------------------------------------
constexpr int XLDE = 40;   // x LDS row stride (ushorts), 80B

__global__ __launch_bounds__(256, 2) void gemm_ait_mfma(
    const float* __restrict__ x, const unsigned short* __restrict__ Wb2,
    const float* __restrict__ bias, const float* __restrict__ u,
    float* __restrict__ ait)
{
    __shared__ __align__(16) unsigned short wsh[2][16384];   // 64 KiB
    __shared__ __align__(16) unsigned short xs[2][64 * XLDE];// 10 KiB
    __shared__ float rowpart[4][64];

    const int tid  = threadIdx.x;
    const int wave = tid >> 6;
    const int lane = tid & 63;
    const int half = lane >> 5;
    const int nl   = lane & 31;
    const int m0   = blockIdx.x * 64;

    f32x16 acc[2][4];
    #pragma unroll
    for (int mi = 0; mi < 2; ++mi)
        #pragma unroll
        for (int ni = 0; ni < 4; ++ni)
            #pragma unroll
            for (int r = 0; r < 16; ++r) acc[mi][ni][r] = 0.f;

    const int xr = tid >> 2;     // 0..63
    const int xc = tid & 3;      // 0..3 (8-elem k-chunk)
    const float* xbase = x + (size_t)(m0 + xr) * D_DIM + xc * 8;

    // prologue: DMA W stage 0, load x stage 0
    #pragma unroll
    for (int i = 0; i < 8; ++i)
        ASYNC_CP16(Wb2 + tid * 8 + i * 2048, &wsh[0][tid * 8 + i * 2048]);
    float4 px0 = *(const float4*)(xbase);
    float4 px1 = *(const float4*)(xbase + 4);

    for (int s = 0; s < 16; ++s) {
        const int pb = s & 1;
        // stage x (fp32 -> bf16); waits px (and, being older, the W DMA)
        {
            ushort8v pk;
            pk[0] = f2bf(px0.x); pk[1] = f2bf(px0.y); pk[2] = f2bf(px0.z); pk[3] = f2bf(px0.w);
            pk[4] = f2bf(px1.x); pk[5] = f2bf(px1.y); pk[6] = f2bf(px1.z); pk[7] = f2bf(px1.w);
            *(ushort8v*)&xs[pb][xr * XLDE + xc * 8] = pk;
        }
        __syncthreads();   // xs[pb] + wsh[pb] ready (vmcnt/lgkm drained)

        if (s + 1 < 16) {
            const unsigned short* wsrc = Wb2 + (size_t)(s + 1) * 16384;
            #pragma unroll
            for (int i = 0; i < 8; ++i)
                ASYNC_CP16(wsrc + tid * 8 + i * 2048, &wsh[1 - pb][tid * 8 + i * 2048]);
            px0 = *(const float4*)(xbase + (s + 1) * 32);
            px1 = *(const float4*)(xbase + (s + 1) * 32 + 4);
        }

        #pragma unroll
        for (int ks = 0; ks < 2; ++ks) {
            short8v af[2], bfr[4];
            #pragma unroll
            for (int mi = 0; mi < 2; ++mi)
                af[mi] = *(const short8v*)&xs[pb][(mi * 32 + nl) * XLDE + ks * 16 + half * 8];
            #pragma unroll
            for (int ni = 0; ni < 4; ++ni)
                bfr[ni] = *(const short8v*)&wsh[pb][(((wave * 4 + ni) * 2 + ks) * 2 + half) * 256 + nl * 8];
            #pragma unroll
            for (int mi = 0; mi < 2; ++mi)
                #pragma unroll
                for (int ni = 0; ni < 4; ++ni)
                    acc[mi][ni] = __builtin_amdgcn_mfma_f32_32x32x16_bf16(
                        af[mi], bfr[ni], acc[mi][ni], 0, 0, 0);
        }
        // no second barrier: next iter writes the OTHER buffers; the next
        // __syncthreads() orders everything.
    }

    // epilogue: ait[m] = sum_e tanh(C[m][e]+bias[e]) * u[e]
    // C/D layout: col = lane&31, row = (reg&3) + 8*(reg>>2) + 4*(lane>>5)
    float rowsum[2][16];
    #pragma unroll
    for (int mi = 0; mi < 2; ++mi)
        #pragma unroll
        for (int r = 0; r < 16; ++r) rowsum[mi][r] = 0.f;

    #pragma unroll
    for (int mi = 0; mi < 2; ++mi) {
        #pragma unroll
        for (int ni = 0; ni < 4; ++ni) {
            int col = wave * 128 + ni * 32 + nl;
            float be = bias[col], ue = u[col];
            #pragma unroll
            for (int r = 0; r < 16; ++r)
                rowsum[mi][r] += fast_tanh(acc[mi][ni][r] + be) * ue;
        }
    }
    #pragma unroll
    for (int mi = 0; mi < 2; ++mi)
        #pragma unroll
        for (int r = 0; r < 16; ++r) {
            float v = rowsum[mi][r];
            v += __shfl_xor(v, 1, 64);
            v += __shfl_xor(v, 2, 64);
            v += __shfl_xor(v, 4, 64);
            v += __shfl_xor(v, 8, 64);
            v += __shfl_xor(v, 16, 64);
            rowsum[mi][r] = v;
        }
    if (nl == 0) {
        #pragma unroll
        for (int mi = 0; mi < 2; ++mi)
            #pragma unroll
            for (int r = 0; r < 16; ++r) {
                int row = mi * 32 + (r & 3) + 8 * (r >> 2) + 4 * half;
                rowpart[wave][row] = rowsum[mi][r];
            }
    }
    __syncthreads();
    if (tid < 64)
        ait[m0 + tid] = rowpart[0][tid] + rowpart[1][tid] + rowpart[2][tid] + rowpart[3][tid];
}

// ---- fp32 fallback GEMM (only if workspace is unexpectedly tiny) ----
__global__ __launch_bounds__(256) void gemm_ait_f32(
    const float* __restrict__ x, const float* __restrict__ W,
    const float* __restrict__ bias, const float* __restrict__ u,
    float* __restrict__ ait)
{
    __shared__ float xsf[64][68];
    __shared__ float wshf[64][132];
    const int tid = threadIdx.x;
    const int tx = tid & 15, ty = tid >> 4;
    const int m0 = blockIdx.x * 64;
    float rowsum[4] = {0.f, 0.f, 0.f, 0.f};
    for (int e0 = 0; e0 < D_DIM; e0 += 128) {
        float acc[4][8];
        #pragma unroll
        for (int i = 0; i < 4; ++i)
            #pragma unroll
            for (int j = 0; j < 8; ++j) acc[i][j] = 0.f;
        for (int kc = 0; kc < D_DIM; kc += 64) {
            #pragma unroll
            for (int i = 0; i < 4; ++i) {
                int idx = tid + i * 256;
                int r = idx >> 4, c = (idx & 15) * 4;
                *(float4*)&xsf[r][c] = *(const float4*)(x + (size_t)(m0 + r) * D_DIM + kc + c);
            }
            #pragma unroll
            for (int i = 0; i < 8; ++i) {
                int idx = tid + i * 256;
                int r = idx >> 5, c = (idx & 31) * 4;
                *(float4*)&wshf[r][c] = *(const float4*)(W + (size_t)(kc + r) * D_DIM + e0 + c);
            }
            __syncthreads();
            #pragma unroll 4
            for (int k = 0; k < 64; ++k) {
                float xv[4];
                #pragma unroll
                for (int i = 0; i < 4; ++i) xv[i] = xsf[ty * 4 + i][k];
                float4 w0 = *(const float4*)&wshf[k][tx * 8];
                float4 w1 = *(const float4*)&wshf[k][tx * 8 + 4];
                #pragma unroll
                for (int i = 0; i < 4; ++i) {
                    acc[i][0] += xv[i] * w0.x; acc[i][1] += xv[i] * w0.y;
                    acc[i][2] += xv[i] * w0.z; acc[i][3] += xv[i] * w0.w;
                    acc[i][4] += xv[i] * w1.x; acc[i][5] += xv[i] * w1.y;
                    acc[i][6] += xv[i] * w1.z; acc[i][7] += xv[i] * w1.w;
                }
            }
            __syncthreads();
        }
        #pragma unroll
        for (int j = 0; j < 8; ++j) {
            int e = e0 + tx * 8 + j;
            float be = bias[e], ue = u[e];
            #pragma unroll
            for (int i = 0; i < 4; ++i) rowsum[i] += tanhf(acc[i][j] + be) * ue;
        }
    }
    float* red = &xsf[0][0];
    #pragma unroll
    for (int i = 0; i < 4; ++i) red[(ty * 4 + i) * 16 + tx] = rowsum[i];
    __syncthreads();
    if (tid < 64) {
        float s = 0.f;
        #pragma unroll
        for (int j = 0; j < 16; ++j) s += red[tid * 16 + j];
        ait[m0 + tid] = s;
    }
}

// ---- softmax over T (in-place, plain exp + eps) ----
__global__ __launch_bounds__(256) void softmax_kernel(float* __restrict__ ait, int T)
{
    const int b = blockIdx.x;
    float* p = ait + (size_t)b * T;
    const int tid = threadIdx.x;
    float ev[8];
    float local = 0.f;
    #pragma unroll
    for (int i = 0; i < 8; ++i) {
        ev[i] = expf(p[tid + i * 256]);
        local += ev[i];
    }
    #pragma unroll
    for (int off = 32; off > 0; off >>= 1)
        local += __shfl_down(local, off, 64);
    __shared__ float wsum[4];
    const int wv = tid >> 6, lane = tid & 63;
    if (lane == 0) wsum[wv] = local;
    __syncthreads();
    float total = wsum[0] + wsum[1] + wsum[2] + wsum[3];
    float inv = 1.0f / (total + 1e-7f);
    #pragma unroll
    for (int i = 0; i < 8; ++i) p[tid + i * 256] = ev[i] * inv;
}

// ---- pooling: 64-t chunk per block, 2 streams, deep unroll ----
__device__ inline float4 pool_accum(const float* __restrict__ x,
                                    const float* __restrict__ a,
                                    int b, int c, int tid, int T) {
    const int th = tid >> 7;
    const int d = (tid & 127) * 4;
    const float* xp = x + ((size_t)b * T + c * 64) * D_DIM + d;
    const float* ap = a + (size_t)b * T + c * 64;
    float4 acc = {0.f, 0.f, 0.f, 0.f};
    #pragma unroll 8
    for (int t = th; t < 64; t += 2) {
        float s = ap[t];
        float4 xv = *(const float4*)(xp + (size_t)t * D_DIM);
        acc.x += xv.x * s; acc.y += xv.y * s;
        acc.z += xv.z * s; acc.w += xv.w * s;
    }
    return acc;
}

__global__ __launch_bounds__(256) void pool_partial_kernel(
    const float* __restrict__ x, const float* __restrict__ a,
    float* __restrict__ partial, int T)
{
    const int chunks = T >> 6;               // 32
    const int b = blockIdx.x / chunks;
    const int c = blockIdx.x % chunks;
    const int tid = threadIdx.x;
    float4 acc = pool_accum(x, a, b, c, tid, T);
    __shared__ float4 tmp[128];
    if ((tid >> 7) == 1) tmp[tid & 127] = acc;
    __syncthreads();
    if ((tid >> 7) == 0) {
        float4 o = tmp[tid];
        acc.x += o.x; acc.y += o.y; acc.z += o.z; acc.w += o.w;
        *(float4*)(partial + (size_t)blockIdx.x * D_DIM + tid * 4) = acc;
    }
}

__global__ __launch_bounds__(256) void pool_reduce_kernel(
    const float* __restrict__ partial, float* __restrict__ out, int chunks)
{
    const int b = blockIdx.x;
    const int tid = threadIdx.x;
    const int d = tid * 2;
    float2 acc = {0.f, 0.f};
    for (int c = 0; c < chunks; ++c) {
        float2 v = *(const float2*)(partial + ((size_t)b * chunks + c) * D_DIM + d);
        acc.x += v.x; acc.y += v.y;
    }
    *(float2*)(out + (size_t)b * D_DIM + d) = acc;
}

__global__ __launch_bounds__(256) void pool_atomic_kernel(
    const float* __restrict__ x, const float* __restrict__ a,
    float* __restrict__ out, int T)
{
    const int chunks = T >> 6;
    const int b = blockIdx.x / chunks;
    const int c = blockIdx.x % chunks;
    const int tid = threadIdx.x;
    float4 acc = pool_accum(x, a, b, c, tid, T);
    __shared__ float4 tmp[128];
    if ((tid >> 7) == 1) tmp[tid & 127] = acc;
    __syncthreads();
    if ((tid >> 7) == 0) {
        float4 o = tmp[tid];
        float* op = out + (size_t)b * D_DIM + tid * 4;
        atomicAdd(op + 0, acc.x + o.x);
        atomicAdd(op + 1, acc.y + o.y);
        atomicAdd(op + 2, acc.z + o.z);
        atomicAdd(op + 3, acc.w + o.w);
    }
}

extern "C" void kernel_launch(void* const* d_in, const int* in_sizes, int n_in,
                              void* d_out, int out_size, void* d_ws, size_t ws_size,
                              hipStream_t stream)
{
    const float* x    = (const float*)d_in[0];
    const float* W    = (const float*)d_in[1];
    const float* bias = (const float*)d_in[2];
    const float* u    = (const float*)d_in[3];
    float* out = (float*)d_out;

    const int Dd = in_sizes[2];          // 512
    const int M  = in_sizes[0] / Dd;     // 65536
    const int B  = out_size / Dd;        // 32
    const int T  = M / B;                // 2048
    const int chunks = T >> 6;           // 32

    const size_t wb_bytes   = (size_t)Dd * Dd * sizeof(unsigned short);   // 512 KiB
    const size_t ait_bytes  = (size_t)M * sizeof(float);                  // 256 KiB
    const size_t part_bytes = (size_t)B * chunks * Dd * sizeof(float);    // 2 MiB

    if (ws_size >= wb_bytes + ait_bytes) {
        unsigned short* Wb2 = (unsigned short*)d_ws;
        float* ait = (float*)((char*)d_ws + wb_bytes);
        wt_kernel<<<dim3(16), dim3(256), 0, stream>>>(W, Wb2);
        gemm_ait_mfma<<<dim3(M / 64), dim3(256), 0, stream>>>(x, Wb2, bias, u, ait);
        softmax_kernel<<<dim3(B), dim3(256), 0, stream>>>(ait, T);
        if (ws_size >= wb_bytes + ait_bytes + part_bytes) {
            float* partial = (float*)((char*)d_ws + wb_bytes + ait_bytes);
            pool_partial_kernel<<<dim3(B * chunks), dim3(256), 0, stream>>>(x, ait, partial, T);
            pool_reduce_kernel<<<dim3(B), dim3(256), 0, stream>>>(partial, out, chunks);
        } else {
            hipMemsetAsync(d_out, 0, (size_t)out_size * sizeof(float), stream);
            pool_atomic_kernel<<<dim3(B * chunks), dim3(256), 0, stream>>>(x, ait, out, T);
        }
    } else {
        float* ait = (float*)d_ws;
        gemm_ait_f32<<<dim3(M / 64), dim3(256), 0, stream>>>(x, W, bias, u, ait);
        softmax_kernel<<<dim3(B), dim3(256), 0, stream>>>(ait, T);
        hipMemsetAsync(d_out, 0, (size_t)out_size * sizeof(float), stream);
        pool_atomic_kernel<<<dim3(B * chunks), dim3(256), 0, stream>>>(x, ait, out, T);
    }
}

// Round 8
// 260.148 us; speedup vs baseline: 1.0547x; 1.0547x over previous
//
#include <hip/hip_runtime.h>
#include <math.h>

#define D_DIM 512

typedef short short8v __attribute__((ext_vector_type(8)));
typedef unsigned short ushort8v __attribute__((ext_vector_type(8)));
typedef float f32x16 __attribute__((ext_vector_type(16)));

__device__ inline unsigned short f2bf(float f) {
    union { float f; unsigned int u; } a; a.f = f;
    unsigned int u = a.u;
    unsigned int r = (u + 0x7fffu + ((u >> 16) & 1u)) >> 16;  // RNE
    return (unsigned short)r;
}

// fast tanh: 1 - 2/(e^{2y}+1); saturates correctly at +-1
__device__ inline float fast_tanh(float y) {
    float e2 = __expf(2.f * y);
    return 1.f - __fdividef(2.f, e2 + 1.f);
}

// async 16B global -> LDS (HW scatters lane i at wave-uniform base + i*16)
#define ASYNC_CP16(gp, lp) \
    __builtin_amdgcn_global_load_lds( \
        (const __attribute__((address_space(1))) void*)(gp), \
        (__attribute__((address_space(3))) void*)(lp), 16, 0, 0)

// ---------------------------------------------------------------------------
// wt: W[k][e] fp32 -> Wb2 stage-tiled bf16.
// Wb2 ushort idx: stage s (32 k) * 16384 + chunk(((nt*2+ks)*2+half)*32+nl)*8+j
// holding W[k=32s+16ks+8half+j][e=32nt+nl].
// ---------------------------------------------------------------------------
__global__ __launch_bounds__(1024) void wt_kernel(const float* __restrict__ W,
                                                  unsigned short* __restrict__ Wb2) {
    __shared__ __align__(16) unsigned short lbuf[16384];   // 32 KiB
    const int s = blockIdx.x;          // 0..15
    const int tid = threadIdx.x;
    #pragma unroll
    for (int i = 0; i < 4; ++i) {
        int flat = tid + i * 1024;     // 0..4095 float4-chunks of this stage
        int kr = flat >> 7;            // 0..31
        int e4 = (flat & 127) * 4;
        float4 v = *(const float4*)(W + (size_t)(s * 32 + kr) * D_DIM + e4);
        int ks = kr >> 4, half = (kr >> 3) & 1, j = kr & 7;
        float vv[4] = {v.x, v.y, v.z, v.w};
        #pragma unroll
        for (int q = 0; q < 4; ++q) {
            int e = e4 + q, nt = e >> 5, nl = e & 31;
            lbuf[(((nt * 2 + ks) * 2 + half) * 32 + nl) * 8 + j] = f2bf(vv[q]);
        }
    }
    __syncthreads();
    #pragma unroll
    for (int i = 0; i < 2; ++i) {
        int c = tid + i * 1024;        // 0..2047 8-ushort chunks
        *(ushort8v*)(Wb2 + (size_t)s * 16384 + c * 8) = *(const ushort8v*)&lbuf[c * 8];
    }
}

// ---------------------------------------------------------------------------
// MFMA GEMM + fused tanh/dot-u epilogue.
// 512 thr = 8 waves; tile 128 rows x 512 cols; K in 16 stages of 32.
// wave (wr,wc): rows wr*64 + {0..63}, cols wc*128 + {0..127} as 2x4 32x32 tiles.
// W via async global_load_lds, double-buffered; x fp32->bf16 in-register,
// double-buffered. One barrier per stage.
// ---------------------------------------------------------------------------
constexpr int XLDE = 40;   // x LDS row stride (ushorts), 80B

__global__ __launch_bounds__(512, 2) void gemm_ait_mfma(
    const float* __restrict__ x, const unsigned short* __restrict__ Wb2,
    const float* __restrict__ bias, const float* __restrict__ u,
    float* __restrict__ ait)
{
    __shared__ __align__(16) unsigned short wsh[2][16384];    // 64 KiB
    __shared__ __align__(16) unsigned short xs[2][128 * XLDE];// 20 KiB
    __shared__ float rowpart[4][128];                          // 2 KiB

    const int tid  = threadIdx.x;
    const int wave = tid >> 6;        // 0..7
    const int lane = tid & 63;
    const int half = lane >> 5;
    const int nl   = lane & 31;
    const int wr   = wave >> 2;       // row group (0/1)
    const int wc   = wave & 3;        // col group (0..3)
    const int m0   = blockIdx.x * 128;

    f32x16 acc[2][4];
    #pragma unroll
    for (int mi = 0; mi < 2; ++mi)
        #pragma unroll
        for (int ni = 0; ni < 4; ++ni)
            #pragma unroll
            for (int r = 0; r < 16; ++r) acc[mi][ni][r] = 0.f;

    const int xr = tid >> 2;     // 0..127
    const int xc = tid & 3;      // 0..3 (8-elem k-chunk)
    const float* xbase = x + (size_t)(m0 + xr) * D_DIM + xc * 8;

    // prologue: DMA W stage 0 (4 x 16B per thread), load x stage 0
    #pragma unroll
    for (int i = 0; i < 4; ++i)
        ASYNC_CP16(Wb2 + tid * 8 + i * 4096, &wsh[0][tid * 8 + i * 4096]);
    float4 px0 = *(const float4*)(xbase);
    float4 px1 = *(const float4*)(xbase + 4);

    for (int s = 0; s < 16; ++s) {
        const int pb = s & 1;
        {
            ushort8v pk;
            pk[0] = f2bf(px0.x); pk[1] = f2bf(px0.y); pk[2] = f2bf(px0.z); pk[3] = f2bf(px0.w);
            pk[4] = f2bf(px1.x); pk[5] = f2bf(px1.y); pk[6] = f2bf(px1.z); pk[7] = f2bf(px1.w);
            *(ushort8v*)&xs[pb][xr * XLDE + xc * 8] = pk;
        }
        __syncthreads();   // xs[pb] + wsh[pb] ready

        if (s + 1 < 16) {
            const unsigned short* wsrc = Wb2 + (size_t)(s + 1) * 16384;
            #pragma unroll
            for (int i = 0; i < 4; ++i)
                ASYNC_CP16(wsrc + tid * 8 + i * 4096, &wsh[1 - pb][tid * 8 + i * 4096]);
            px0 = *(const float4*)(xbase + (s + 1) * 32);
            px1 = *(const float4*)(xbase + (s + 1) * 32 + 4);
        }

        #pragma unroll
        for (int ks = 0; ks < 2; ++ks) {
            short8v af[2], bfr[4];
            #pragma unroll
            for (int mi = 0; mi < 2; ++mi)
                af[mi] = *(const short8v*)&xs[pb][(wr * 64 + mi * 32 + nl) * XLDE + ks * 16 + half * 8];
            #pragma unroll
            for (int ni = 0; ni < 4; ++ni)
                bfr[ni] = *(const short8v*)&wsh[pb][(((wc * 4 + ni) * 2 + ks) * 2 + half) * 256 + nl * 8];
            #pragma unroll
            for (int mi = 0; mi < 2; ++mi)
                #pragma unroll
                for (int ni = 0; ni < 4; ++ni)
                    acc[mi][ni] = __builtin_amdgcn_mfma_f32_32x32x16_bf16(
                        af[mi], bfr[ni], acc[mi][ni], 0, 0, 0);
        }
        // next iter writes the other buffers; its barrier orders everything
    }

    // epilogue: ait[m] = sum_e tanh(C[m][e]+bias[e]) * u[e]
    // C/D layout: col = lane&31, row = (reg&3) + 8*(reg>>2) + 4*(lane>>5)
    float rowsum[2][16];
    #pragma unroll
    for (int mi = 0; mi < 2; ++mi)
        #pragma unroll
        for (int r = 0; r < 16; ++r) rowsum[mi][r] = 0.f;

    #pragma unroll
    for (int mi = 0; mi < 2; ++mi) {
        #pragma unroll
        for (int ni = 0; ni < 4; ++ni) {
            int col = wc * 128 + ni * 32 + nl;
            float be = bias[col], ue = u[col];
            #pragma unroll
            for (int r = 0; r < 16; ++r)
                rowsum[mi][r] += fast_tanh(acc[mi][ni][r] + be) * ue;
        }
    }
    #pragma unroll
    for (int mi = 0; mi < 2; ++mi)
        #pragma unroll
        for (int r = 0; r < 16; ++r) {
            float v = rowsum[mi][r];
            v += __shfl_xor(v, 1, 64);
            v += __shfl_xor(v, 2, 64);
            v += __shfl_xor(v, 4, 64);
            v += __shfl_xor(v, 8, 64);
            v += __shfl_xor(v, 16, 64);
            rowsum[mi][r] = v;
        }
    if (nl == 0) {
        #pragma unroll
        for (int mi = 0; mi < 2; ++mi)
            #pragma unroll
            for (int r = 0; r < 16; ++r) {
                int row = wr * 64 + mi * 32 + (r & 3) + 8 * (r >> 2) + 4 * half;
                rowpart[wc][row] = rowsum[mi][r];
            }
    }
    __syncthreads();
    if (tid < 128)
        ait[m0 + tid] = rowpart[0][tid] + rowpart[1][tid] + rowpart[2][tid] + rowpart[3][tid];
}

// ---- fp32 fallback GEMM (only if ws < 768 KiB — never observed) ----
__global__ __launch_bounds__(256) void gemm_ait_f32(
    const float* __restrict__ x, const float* __restrict__ W,
    const float* __restrict__ bias, const float* __restrict__ u,
    float* __restrict__ ait)
{
    __shared__ float xsf[64][68];
    __shared__ float wshf[64][132];
    const int tid = threadIdx.x;
    const int tx = tid & 15, ty = tid >> 4;
    const int m0 = blockIdx.x * 64;
    float rowsum[4] = {0.f, 0.f, 0.f, 0.f};
    for (int e0 = 0; e0 < D_DIM; e0 += 128) {
        float acc[4][8];
        #pragma unroll
        for (int i = 0; i < 4; ++i)
            #pragma unroll
            for (int j = 0; j < 8; ++j) acc[i][j] = 0.f;
        for (int kc = 0; kc < D_DIM; kc += 64) {
            #pragma unroll
            for (int i = 0; i < 4; ++i) {
                int idx = tid + i * 256;
                int r = idx >> 4, c = (idx & 15) * 4;
                *(float4*)&xsf[r][c] = *(const float4*)(x + (size_t)(m0 + r) * D_DIM + kc + c);
            }
            #pragma unroll
            for (int i = 0; i < 8; ++i) {
                int idx = tid + i * 256;
                int r = idx >> 5, c = (idx & 31) * 4;
                *(float4*)&wshf[r][c] = *(const float4*)(W + (size_t)(kc + r) * D_DIM + e0 + c);
            }
            __syncthreads();
            #pragma unroll 4
            for (int k = 0; k < 64; ++k) {
                float xv[4];
                #pragma unroll
                for (int i = 0; i < 4; ++i) xv[i] = xsf[ty * 4 + i][k];
                float4 w0 = *(const float4*)&wshf[k][tx * 8];
                float4 w1 = *(const float4*)&wshf[k][tx * 8 + 4];
                #pragma unroll
                for (int i = 0; i < 4; ++i) {
                    acc[i][0] += xv[i] * w0.x; acc[i][1] += xv[i] * w0.y;
                    acc[i][2] += xv[i] * w0.z; acc[i][3] += xv[i] * w0.w;
                    acc[i][4] += xv[i] * w1.x; acc[i][5] += xv[i] * w1.y;
                    acc[i][6] += xv[i] * w1.z; acc[i][7] += xv[i] * w1.w;
                }
            }
            __syncthreads();
        }
        #pragma unroll
        for (int j = 0; j < 8; ++j) {
            int e = e0 + tx * 8 + j;
            float be = bias[e], ue = u[e];
            #pragma unroll
            for (int i = 0; i < 4; ++i) rowsum[i] += tanhf(acc[i][j] + be) * ue;
        }
    }
    float* red = &xsf[0][0];
    #pragma unroll
    for (int i = 0; i < 4; ++i) red[(ty * 4 + i) * 16 + tx] = rowsum[i];
    __syncthreads();
    if (tid < 64) {
        float s = 0.f;
        #pragma unroll
        for (int j = 0; j < 16; ++j) s += red[tid * 16 + j];
        ait[m0 + tid] = s;
    }
}

// ---- softmax over T (in-place, plain exp + eps) ----
__global__ __launch_bounds__(256) void softmax_kernel(float* __restrict__ ait, int T)
{
    const int b = blockIdx.x;
    float* p = ait + (size_t)b * T;
    const int tid = threadIdx.x;
    float ev[8];
    float local = 0.f;
    #pragma unroll
    for (int i = 0; i < 8; ++i) {
        ev[i] = expf(p[tid + i * 256]);
        local += ev[i];
    }
    #pragma unroll
    for (int off = 32; off > 0; off >>= 1)
        local += __shfl_down(local, off, 64);
    __shared__ float wsum[4];
    const int wv = tid >> 6, lane = tid & 63;
    if (lane == 0) wsum[wv] = local;
    __syncthreads();
    float total = wsum[0] + wsum[1] + wsum[2] + wsum[3];
    float inv = 1.0f / (total + 1e-7f);
    #pragma unroll
    for (int i = 0; i < 8; ++i) p[tid + i * 256] = ev[i] * inv;
}

// ---- pooling: 256-t chunk per block (8/batch, 256 blocks), 2 streams ----
__global__ __launch_bounds__(256) void pool_partial_kernel(
    const float* __restrict__ x, const float* __restrict__ a,
    float* __restrict__ partial, int T)
{
    const int chunks = T >> 8;               // 8
    const int b = blockIdx.x / chunks;
    const int c = blockIdx.x % chunks;
    const int tid = threadIdx.x;
    const int th = tid >> 7;                 // 2 t-streams
    const int d = (tid & 127) * 4;

    const float* xp = x + ((size_t)b * T + c * 256) * D_DIM + d;
    const float* ap = a + (size_t)b * T + c * 256;

    float4 acc = {0.f, 0.f, 0.f, 0.f};
    #pragma unroll 8
    for (int t = th; t < 256; t += 2) {      // 128 iters/stream
        float s = ap[t];
        float4 xv = *(const float4*)(xp + (size_t)t * D_DIM);
        acc.x += xv.x * s; acc.y += xv.y * s;
        acc.z += xv.z * s; acc.w += xv.w * s;
    }
    __shared__ float4 tmp[128];
    if (th == 1) tmp[tid & 127] = acc;
    __syncthreads();
    if (th == 0) {
        float4 o = tmp[tid];
        acc.x += o.x; acc.y += o.y; acc.z += o.z; acc.w += o.w;
        *(float4*)(partial + (size_t)blockIdx.x * D_DIM + tid * 4) = acc;
    }
}

__global__ __launch_bounds__(256) void pool_reduce_kernel(
    const float* __restrict__ partial, float* __restrict__ out, int chunks)
{
    const int b = blockIdx.x;
    const int tid = threadIdx.x;
    const int d = tid * 2;
    float2 acc = {0.f, 0.f};
    for (int c = 0; c < chunks; ++c) {
        float2 v = *(const float2*)(partial + ((size_t)b * chunks + c) * D_DIM + d);
        acc.x += v.x; acc.y += v.y;
    }
    *(float2*)(out + (size_t)b * D_DIM + d) = acc;
}

// ---- fallback pool (tiny-ws path only) ----
__global__ __launch_bounds__(256) void pool_atomic_kernel(
    const float* __restrict__ x, const float* __restrict__ a,
    float* __restrict__ out, int T)
{
    const int chunks = T >> 8;
    const int b = blockIdx.x / chunks;
    const int c = blockIdx.x % chunks;
    const int tid = threadIdx.x;
    const int th = tid >> 7;
    const int d = (tid & 127) * 4;
    const float* xp = x + ((size_t)b * T + c * 256) * D_DIM + d;
    const float* ap = a + (size_t)b * T + c * 256;
    float4 acc = {0.f, 0.f, 0.f, 0.f};
    #pragma unroll 8
    for (int t = th; t < 256; t += 2) {
        float s = ap[t];
        float4 xv = *(const float4*)(xp + (size_t)t * D_DIM);
        acc.x += xv.x * s; acc.y += xv.y * s;
        acc.z += xv.z * s; acc.w += xv.w * s;
    }
    __shared__ float4 tmp[128];
    if (th == 1) tmp[tid & 127] = acc;
    __syncthreads();
    if (th == 0) {
        float4 o = tmp[tid];
        float* op = out + (size_t)b * D_DIM + tid * 4;
        atomicAdd(op + 0, acc.x + o.x);
        atomicAdd(op + 1, acc.y + o.y);
        atomicAdd(op + 2, acc.z + o.z);
        atomicAdd(op + 3, acc.w + o.w);
    }
}

extern "C" void kernel_launch(void* const* d_in, const int* in_sizes, int n_in,
                              void* d_out, int out_size, void* d_ws, size_t ws_size,
                              hipStream_t stream)
{
    const float* x    = (const float*)d_in[0];
    const float* W    = (const float*)d_in[1];
    const float* bias = (const float*)d_in[2];
    const float* u    = (const float*)d_in[3];
    float* out = (float*)d_out;

    const int Dd = in_sizes[2];          // 512
    const int M  = in_sizes[0] / Dd;     // 65536
    const int B  = out_size / Dd;        // 32
    const int T  = M / B;                // 2048
    const int chunks = T >> 8;           // 8

    const size_t wb_bytes  = (size_t)Dd * Dd * sizeof(unsigned short);   // 512 KiB
    const size_t ait_bytes = (size_t)M * sizeof(float);                  // 256 KiB

    if (ws_size >= wb_bytes + ait_bytes) {
        // [0, 512K): Wb2 during GEMM, then reused as pool partials.
        // [512K, 768K): ait (softmax in-place -> a).
        unsigned short* Wb2 = (unsigned short*)d_ws;
        float* ait     = (float*)((char*)d_ws + wb_bytes);
        float* partial = (float*)d_ws;    // reuse after gemm completes

        wt_kernel<<<dim3(16), dim3(1024), 0, stream>>>(W, Wb2);
        gemm_ait_mfma<<<dim3(M / 128), dim3(512), 0, stream>>>(x, Wb2, bias, u, ait);
        softmax_kernel<<<dim3(B), dim3(256), 0, stream>>>(ait, T);
        pool_partial_kernel<<<dim3(B * chunks), dim3(256), 0, stream>>>(x, ait, partial, T);
        pool_reduce_kernel<<<dim3(B), dim3(256), 0, stream>>>(partial, out, chunks);
    } else {
        float* ait = (float*)d_ws;
        gemm_ait_f32<<<dim3(M / 64), dim3(256), 0, stream>>>(x, W, bias, u, ait);
        softmax_kernel<<<dim3(B), dim3(256), 0, stream>>>(ait, T);
        hipMemsetAsync(d_out, 0, (size_t)out_size * sizeof(float), stream);
        pool_atomic_kernel<<<dim3(B * chunks), dim3(256), 0, stream>>>(x, ait, out, T);
    }
}